// Round 6
// baseline (361.559 us; speedup 1.0000x reference)
//
#include <hip/hip_runtime.h>
#include <hip/hip_bf16.h>
#include <math.h>

#define NUM_PM 254
#define NUM_VM 768
#define SEQQ   1024      // NUM_PM + NUM_VM + 2
#define NH     8
#define DD     256
#define DH     32
#define FF     1024
#define NB     8
#define MROWS  (NB*SEQQ) // 8192

typedef unsigned short u16;
typedef __attribute__((ext_vector_type(8))) short bf16x8;
typedef __attribute__((ext_vector_type(4))) float f32x4;

__device__ __forceinline__ float bf2f(u16 u){
    union { float f; unsigned int i; } c; c.i = ((unsigned int)u) << 16; return c.f;
}
__device__ __forceinline__ u16 f2bf(float f){
    union { float f; unsigned int u; } c; c.f = f;
    unsigned int r = c.u + 0x7FFFu + ((c.u >> 16) & 1u);   // RNE
    return (u16)(r >> 16);
}
__device__ __forceinline__ float gelu_tanh(float x){
    float x3 = x*x*x;
    float t = tanhf(0.7978845608028654f*(x + 0.044715f*x3));
    return 0.5f*x*(1.0f+t);
}

#define GLOAD16(gp, lp) __builtin_amdgcn_global_load_lds( \
    (const __attribute__((address_space(1))) void*)(gp), \
    (__attribute__((address_space(3))) void*)(lp), 16, 0, 0)

// ---------------------------------------------------------------- embed + LN1(layer0): wave per row
__global__ void embed_ln_kernel(const float* __restrict__ vm_states,
                                const float* __restrict__ num_step,
                                const float* __restrict__ pm_states,
                                const float* __restrict__ pm_W, const float* __restrict__ pm_b,
                                const float* __restrict__ vm_W, const float* __restrict__ vm_b,
                                const float* __restrict__ g, const float* __restrict__ beta,
                                float* __restrict__ x, u16* __restrict__ h)
{
    int row = blockIdx.x*4 + (threadIdx.x>>6);
    int lane = threadIdx.x & 63;
    int b = row >> 10, s = row & 1023;
    int col = lane*4;
    float4 out;
    if (s == 0){
        float v = num_step[b]; out = (float4){v,v,v,v};
    } else if (s == SEQQ-1){
        out = (float4){-1.f,-1.f,-1.f,-1.f};
    } else {
        const float* in; const float* W; const float* bias;
        if (s <= NUM_PM){ in = pm_states + (size_t)(b*NUM_PM + s-1)*16; W = pm_W; bias = pm_b; }
        else            { in = vm_states + (size_t)(b*NUM_VM + (s-1-NUM_PM))*16; W = vm_W; bias = vm_b; }
        float4 i0 = *(const float4*)in,      i1 = *(const float4*)(in+4);
        float4 i2 = *(const float4*)(in+8),  i3 = *(const float4*)(in+12);
        float in16[16] = {i0.x,i0.y,i0.z,i0.w, i1.x,i1.y,i1.z,i1.w,
                          i2.x,i2.y,i2.z,i2.w, i3.x,i3.y,i3.z,i3.w};
        out = *(const float4*)&bias[col];
        #pragma unroll
        for (int k=0;k<16;k++){
            float4 w4 = *(const float4*)&W[k*DD + col];
            out.x = fmaf(in16[k], w4.x, out.x);
            out.y = fmaf(in16[k], w4.y, out.y);
            out.z = fmaf(in16[k], w4.z, out.z);
            out.w = fmaf(in16[k], w4.w, out.w);
        }
    }
    *(float4*)&x[(size_t)row*DD + col] = out;
    // LN over the row (all 64 lanes hold 4 vals each)
    float s1 = out.x+out.y+out.z+out.w;
    float s2 = fmaf(out.x,out.x, fmaf(out.y,out.y, fmaf(out.z,out.z, out.w*out.w)));
    #pragma unroll
    for (int off=1; off<64; off<<=1){ s1 += __shfl_xor(s1,off); s2 += __shfl_xor(s2,off); }
    float m    = s1*(1.0f/DD);
    float var  = s2*(1.0f/DD) - m*m;
    float rstd = rsqrtf(var + 1e-5f);
    float4 g4 = *(const float4*)&g[col];
    float4 b4 = *(const float4*)&beta[col];
    short4 o;
    o.x = (short)f2bf((out.x-m)*rstd*g4.x + b4.x);
    o.y = (short)f2bf((out.y-m)*rstd*g4.y + b4.y);
    o.z = (short)f2bf((out.z-m)*rstd*g4.z + b4.z);
    o.w = (short)f2bf((out.w-m)*rstd*g4.w + b4.w);
    *(short4*)&h[(size_t)row*DD + col] = o;
}

// ---------------------------------------------------------------- merged transpose-cast (all 4 weight tensors)
__global__ void tcast_all_kernel(const float* __restrict__ Wqkv, const float* __restrict__ Wo,
                                 const float* __restrict__ W1,   const float* __restrict__ W2,
                                 u16* __restrict__ wq, u16* __restrict__ wo,
                                 u16* __restrict__ w1, u16* __restrict__ w2)
{
    __shared__ float t[32][33];
    int id = blockIdx.x;
    const float* in; u16* out; int K, N, layer, tile;
    if (id < 576)       { in=Wqkv; out=wq; K=256;  N=768;  layer=id/192; tile=id%192; }
    else if (id < 768)  { id-=576;  in=Wo; out=wo; K=256;  N=256;  layer=id/64;  tile=id%64;  }
    else if (id < 1536) { id-=768;  in=W1; out=w1; K=256;  N=1024; layer=id/256; tile=id%256; }
    else                { id-=1536; in=W2; out=w2; K=1024; N=256;  layer=id/256; tile=id%256; }
    int ntx = N/32;
    int n0 = (tile % ntx)*32, k0 = (tile / ntx)*32;
    size_t lofs = (size_t)layer * K * N;
    int tx = threadIdx.x & 31, ty = threadIdx.x >> 5;   // ty 0..7
    #pragma unroll
    for (int i=0;i<4;i++)
        t[ty + i*8][tx] = in[lofs + (size_t)(k0 + ty + i*8)*N + n0 + tx];
    __syncthreads();
    #pragma unroll
    for (int i=0;i<4;i++)
        out[lofs + (size_t)(n0 + ty + i*8)*K + k0 + tx] = f2bf(t[tx][ty + i*8]);
}

// ---------------------------------------------------------------- MFMA GEMM 128x128, dbuf 2-phase: C bf16 = A@Bt^T + bias (+gelu)
// EPI: 0 = bias ; 2 = bias + gelu
template<int EPI>
__launch_bounds__(256)
__global__ void mgemm_kernel(const u16* __restrict__ A, const u16* __restrict__ Bt,
                             const float* __restrict__ bias, u16* __restrict__ C,
                             int N, int K)
{
    __shared__ u16 As[2][128][32];
    __shared__ u16 Bs[2][128][32];
    int tid = threadIdx.x;
    int wid = tid >> 6, lane = tid & 63;
    int wr = wid >> 1, wc = wid & 1;            // 2x2 wave grid, wave tile 64x64
    int row0 = blockIdx.y*128, col0 = blockIdx.x*128;
    int l15 = lane & 15, lh = lane >> 4;

    int srow = wid*32 + (lane>>2);
    int skof = (lane&3)*8;
    const u16* Ag = A  + (size_t)(row0 + srow)*K + skof;
    const u16* Bg = Bt + (size_t)(col0 + srow)*K + skof;

#define STAGE_M(buf, k0) do{ \
    GLOAD16(Ag + (k0),          &As[buf][wid*32][0]);    \
    GLOAD16(Ag + (k0) + 16*K,   &As[buf][wid*32+16][0]); \
    GLOAD16(Bg + (k0),          &Bs[buf][wid*32][0]);    \
    GLOAD16(Bg + (k0) + 16*K,   &Bs[buf][wid*32+16][0]); }while(0)

    f32x4 acc[4][4] = {};
    int nk = K >> 5;
    STAGE_M(0, 0);
    __syncthreads();
    for (int kt = 0; kt < nk; kt++){
        int cur = kt & 1;
        if (kt+1 < nk) STAGE_M(cur^1, (kt+1)*32);   // prefetch overlaps MFMA below
        bf16x8 af[4], bfv[4];
        #pragma unroll
        for (int f=0; f<4; f++){
            af[f]  = *(const bf16x8*)&As[cur][wr*64 + f*16 + l15][lh*8];
            bfv[f] = *(const bf16x8*)&Bs[cur][wc*64 + f*16 + l15][lh*8];
        }
        #pragma unroll
        for (int i=0;i<4;i++)
            #pragma unroll
            for (int j=0;j<4;j++)
                acc[i][j] = __builtin_amdgcn_mfma_f32_16x16x32_bf16(af[i], bfv[j], acc[i][j], 0,0,0);
        __syncthreads();
    }
#undef STAGE_M

    #pragma unroll
    for (int i=0;i<4;i++){
        #pragma unroll
        for (int j=0;j<4;j++){
            int col = col0 + wc*64 + j*16 + l15;
            float bb = bias[col];
            #pragma unroll
            for (int r=0;r<4;r++){
                int row = row0 + wr*64 + i*16 + lh*4 + r;
                float v = acc[i][j][r] + bb;
                if (EPI==2) v = gelu_tanh(v);
                C[(size_t)row*N + col] = f2bf(v);
            }
        }
    }
}

// ---------------------------------------------------------------- MFMA GEMM 32x256 + residual + fused LN epilogue
// x[M,256] += A@Bt^T + bias ; if LN_OUT: h = LN(x_new) in bf16
template<int LN_OUT>
__launch_bounds__(256)
__global__ void mgemm2ln_kernel(const u16* __restrict__ A, const u16* __restrict__ Bt,
                                const float* __restrict__ bias,
                                const float* __restrict__ g, const float* __restrict__ beta,
                                float* __restrict__ x, u16* __restrict__ h, int K)
{
    __shared__ u16 As[2][32][32];
    __shared__ u16 Bs[2][256][32];
    __shared__ float part1[32][4], part2[32][4];
    int tid = threadIdx.x;
    int wid = tid >> 6, lane = tid & 63;
    int row0 = blockIdx.x*32;
    int l15 = lane & 15, lh = lane >> 4;

    // staging: waves 0,1 -> A rows (16 each); all waves -> 4x16 B rows
    const u16* Ag = A + (size_t)(row0 + wid*16 + (lane>>2))*K + (lane&3)*8;
    const u16* Bg = Bt + (size_t)(wid*64 + (lane>>2))*K + (lane&3)*8;

#define STAGE_L(buf, k0) do{ \
    if (wid < 2) GLOAD16(Ag + (k0), &As[buf][wid*16][0]); \
    GLOAD16(Bg + (k0),          &Bs[buf][wid*64][0]);     \
    GLOAD16(Bg + (k0) + 16*K,   &Bs[buf][wid*64+16][0]);  \
    GLOAD16(Bg + (k0) + 32*K,   &Bs[buf][wid*64+32][0]);  \
    GLOAD16(Bg + (k0) + 48*K,   &Bs[buf][wid*64+48][0]);  }while(0)

    f32x4 acc[2][4] = {};
    int nk = K >> 5;
    STAGE_L(0, 0);
    __syncthreads();
    for (int kt = 0; kt < nk; kt++){
        int cur = kt & 1;
        if (kt+1 < nk) STAGE_L(cur^1, (kt+1)*32);
        bf16x8 af[2], bfv[4];
        #pragma unroll
        for (int i=0;i<2;i++)
            af[i] = *(const bf16x8*)&As[cur][i*16 + l15][lh*8];
        #pragma unroll
        for (int j=0;j<4;j++)
            bfv[j] = *(const bf16x8*)&Bs[cur][wid*64 + j*16 + l15][lh*8];
        #pragma unroll
        for (int i=0;i<2;i++)
            #pragma unroll
            for (int j=0;j<4;j++)
                acc[i][j] = __builtin_amdgcn_mfma_f32_16x16x32_bf16(af[i], bfv[j], acc[i][j], 0,0,0);
        __syncthreads();
    }
#undef STAGE_L

    // pass 1: v = acc + bias + x ; write x ; accumulate row partial sums
    float s1a[2][4] = {}, s2a[2][4] = {};
    #pragma unroll
    for (int i=0;i<2;i++){
        #pragma unroll
        for (int j=0;j<4;j++){
            int col = wid*64 + j*16 + l15;
            float bb = bias[col];
            #pragma unroll
            for (int r=0;r<4;r++){
                int row = row0 + i*16 + lh*4 + r;
                size_t idx = (size_t)row*DD + col;
                float v = acc[i][j][r] + bb + x[idx];
                x[idx] = v;
                acc[i][j][r] = v;
                if (LN_OUT){
                    s1a[i][r] += v;
                    s2a[i][r] = fmaf(v, v, s2a[i][r]);
                }
            }
        }
    }
    if (LN_OUT){
        #pragma unroll
        for (int i=0;i<2;i++)
            #pragma unroll
            for (int r=0;r<4;r++){
                float s1 = s1a[i][r], s2 = s2a[i][r];
                s1 += __shfl_xor(s1,1); s2 += __shfl_xor(s2,1);
                s1 += __shfl_xor(s1,2); s2 += __shfl_xor(s2,2);
                s1 += __shfl_xor(s1,4); s2 += __shfl_xor(s2,4);
                s1 += __shfl_xor(s1,8); s2 += __shfl_xor(s2,8);
                if (l15 == 0){
                    part1[i*16 + lh*4 + r][wid] = s1;
                    part2[i*16 + lh*4 + r][wid] = s2;
                }
            }
        __syncthreads();
        #pragma unroll
        for (int i=0;i<2;i++){
            #pragma unroll
            for (int r=0;r<4;r++){
                int rl = i*16 + lh*4 + r;
                float s1 = part1[rl][0]+part1[rl][1]+part1[rl][2]+part1[rl][3];
                float s2 = part2[rl][0]+part2[rl][1]+part2[rl][2]+part2[rl][3];
                float m    = s1*(1.0f/DD);
                float var  = s2*(1.0f/DD) - m*m;
                float rstd = rsqrtf(var + 1e-5f);
                #pragma unroll
                for (int j=0;j<4;j++){
                    int col = wid*64 + j*16 + l15;
                    float hv = (acc[i][j][r]-m)*rstd*g[col] + beta[col];
                    h[(size_t)(row0+rl)*DD + col] = f2bf(hv);
                }
            }
        }
    }
}

// ---------------------------------------------------------------- group build: one block per batch
__global__ void group_build_kernel(const int* __restrict__ rel, const unsigned char* __restrict__ mask,
                                   int* __restrict__ counts, int* __restrict__ offs,
                                   int* __restrict__ members)
{
    __shared__ int cntS[256], offS[256], wsum[4];
    int b = blockIdx.x, tid = threadIdx.x;     // 1024 threads
    if (tid < 256) cntS[tid] = 0;
    __syncthreads();
    int s = tid, c = -1, p = -1;
    bool valid = (s != 0) && (s != SEQQ-1);
    if (valid && s >= 1+NUM_PM && mask[b*NUM_VM + (s-1-NUM_PM)]) valid = false;
    if (valid){
        c = rel[b*(SEQQ-2) + s-1];
        p = atomicAdd(&cntS[c], 1);
    }
    __syncthreads();
    if (tid < 256){
        int v = cntS[tid];
        int incl = v;
        #pragma unroll
        for (int d=1; d<64; d<<=1){
            int n = __shfl_up(incl, d);
            if ((tid & 63) >= d) incl += n;
        }
        offS[tid] = incl - v;                   // exclusive within wave
        if ((tid & 63) == 63) wsum[tid>>6] = incl;
    }
    __syncthreads();
    if (tid < 256){
        int w = tid >> 6, base = 0;
        #pragma unroll
        for (int i=0;i<4;i++) if (i < w) base += wsum[i];
        offS[tid] += base;
    }
    __syncthreads();
    if (valid) members[b*SEQQ + offS[c] + p] = s;
    if (tid < 256){
        counts[b*256 + tid] = cntS[tid];
        offs[b*256 + tid]   = offS[tid];
    }
}

// ---------------------------------------------------------------- attention (gathered group-sparse, bf16, chunked prefetch)
__launch_bounds__(256)
__global__ void attn_kernel(const u16* __restrict__ qkv, const int* __restrict__ rel,
                            const int* __restrict__ counts, const int* __restrict__ offs,
                            const int* __restrict__ members, u16* __restrict__ o)
{
    int gq = blockIdx.x*4 + (threadIdx.x >> 6);
    int lane = threadIdx.x & 63;
    int b = gq >> 10, s = gq & 1023;
    const float scale = 0.17677669529663687f;       // 1/sqrt(32)

    const u16* base = qkv + (size_t)(b*SEQQ + s)*768 + lane*4;
    short4 q4i = *(const short4*)base;
    float qx = bf2f((u16)q4i.x)*scale, qy = bf2f((u16)q4i.y)*scale,
          qz = bf2f((u16)q4i.z)*scale, qw = bf2f((u16)q4i.w)*scale;

    int cnt; const int* mlist = nullptr;
    if (s == 0 || s == SEQQ-1) { cnt = 1; }
    else {
        int c = rel[b*(SEQQ-2) + s-1];
        cnt   = counts[b*256 + c];
        mlist = members + b*SEQQ + offs[b*256 + c];
    }

    float m_run = -1e30f, l_run = 0.f;
    float ax=0.f, ay=0.f, az=0.f, aw=0.f;
    for (int j0 = 0; j0 < cnt; j0 += 4){
        short4 k4[4], v4[4];
        #pragma unroll
        for (int k=0;k<4;k++){
            int jj = j0 + k; jj = (jj < cnt) ? jj : (cnt-1);
            int mi = mlist ? mlist[jj] : s;
            const u16* kb = qkv + (size_t)(b*SEQQ + mi)*768 + 256 + lane*4;
            k4[k] = *(const short4*)kb;
            v4[k] = *(const short4*)(kb + 256);
        }
        #pragma unroll
        for (int k=0;k<4;k++){
            if (j0 + k < cnt){
                float sc = qx*bf2f((u16)k4[k].x) + qy*bf2f((u16)k4[k].y)
                         + qz*bf2f((u16)k4[k].z) + qw*bf2f((u16)k4[k].w);
                sc += __shfl_xor(sc, 1);
                sc += __shfl_xor(sc, 2);
                sc += __shfl_xor(sc, 4);
                float mn = fmaxf(m_run, sc);
                float corr = __expf(m_run - mn);
                float p = __expf(sc - mn);
                l_run = l_run*corr + p;
                ax = ax*corr + p*bf2f((u16)v4[k].x);
                ay = ay*corr + p*bf2f((u16)v4[k].y);
                az = az*corr + p*bf2f((u16)v4[k].z);
                aw = aw*corr + p*bf2f((u16)v4[k].w);
                m_run = mn;
            }
        }
    }
    float inv = (l_run > 0.f) ? 1.0f/l_run : 0.f;
    u16* orow = o + (size_t)(b*SEQQ + s)*DD + lane*4;
    short4 outv;
    outv.x = (short)f2bf(ax*inv); outv.y = (short)f2bf(ay*inv);
    outv.z = (short)f2bf(az*inv); outv.w = (short)f2bf(aw*inv);
    *(short4*)orow = outv;
}

// ---------------------------------------------------------------- head (x f32)
__global__ void out_kernel(const float* __restrict__ x,
                           const float* __restrict__ out_W, const float* __restrict__ out_b,
                           const float* __restrict__ crit_W, const float* __restrict__ crit_b,
                           float* __restrict__ out)
{
    int gidx = blockIdx.x*4 + (threadIdx.x>>6);
    int lane = threadIdx.x & 63;
    if (gidx >= NB*769) return;
    int b = gidx / 769, j = gidx % 769;
    int srow; const float* Wp; float bb;
    if (j < 768){ srow = b*SEQQ + 1 + NUM_PM + j; Wp = out_W; bb = out_b[0]; }
    else        { srow = b*SEQQ + SEQQ-1;         Wp = crit_W; bb = crit_b[0]; }
    const float* xr = x + (size_t)srow*DD;
    float4 xv = *(const float4*)&xr[lane*4];
    float4 wv = *(const float4*)&Wp[lane*4];
    float sdot = xv.x*wv.x + xv.y*wv.y + xv.z*wv.z + xv.w*wv.w;
    #pragma unroll
    for (int off=32; off; off>>=1) sdot += __shfl_down(sdot, off);
    if (lane==0) out[gidx] = sdot + bb;
}

// ---------------------------------------------------------------- launch
extern "C" void kernel_launch(void* const* d_in, const int* in_sizes, int n_in,
                              void* d_out, int out_size, void* d_ws, size_t ws_size,
                              hipStream_t stream)
{
    const float* vm_states = (const float*)d_in[0];
    const float* num_step  = (const float*)d_in[1];
    const float* pm_states = (const float*)d_in[2];
    const int*   rel       = (const int*)d_in[3];
    const unsigned char* mask = (const unsigned char*)d_in[4];
    const float* pm_W = (const float*)d_in[5];
    const float* pm_b = (const float*)d_in[6];
    const float* vm_W = (const float*)d_in[7];
    const float* vm_b = (const float*)d_in[8];
    const float* Wqkv = (const float*)d_in[9];
    const float* bqkv = (const float*)d_in[10];
    const float* Wo   = (const float*)d_in[11];
    const float* bo   = (const float*)d_in[12];
    const float* ln1g = (const float*)d_in[13];
    const float* ln1b = (const float*)d_in[14];
    const float* ln2g = (const float*)d_in[15];
    const float* ln2b = (const float*)d_in[16];
    const float* W1   = (const float*)d_in[17];
    const float* b1   = (const float*)d_in[18];
    const float* W2   = (const float*)d_in[19];
    const float* b2   = (const float*)d_in[20];
    const float* out_W = (const float*)d_in[21];
    const float* out_b = (const float*)d_in[22];
    const float* crit_W = (const float*)d_in[23];
    const float* crit_b = (const float*)d_in[24];

    char* ws = (char*)d_ws;
    const size_t MB = 1024*1024;
    float* x    = (float*)(ws);                      // [8192][256] f32   :  0..8 MB
    u16*   hbuf = (u16*)(ws + 8*MB);                 // [8192][256] bf16  :  8..12
    u16*   aout = (u16*)(ws + 12*MB);                // [8192][256] bf16  : 12..16
    u16*   qkv  = (u16*)(ws + 16*MB);                // [8192][768] bf16  : 16..28
    u16*   ff1  = (u16*)(ws + 28*MB);                // [8192][1024] bf16 : 28..44
    u16*   wq   = (u16*)(ws + 44*MB);                // [3][768][256]
    u16*   wo   = wq + (size_t)3*768*256;            // [3][256][256]
    u16*   w1   = wo + (size_t)3*256*256;            // [3][1024][256]
    u16*   w2   = w1 + (size_t)3*1024*256;           // [3][256][1024]
    int*   counts  = (int*)(ws + 50*MB);             // [8][256]
    int*   offs    = counts + NB*256;
    int*   members = offs   + NB*256;                // [8][1024]

    tcast_all_kernel<<<2304, 256, 0, stream>>>(Wqkv, Wo, W1, W2, wq, wo, w1, w2);
    group_build_kernel<<<NB, 1024, 0, stream>>>(rel, mask, counts, offs, members);
    embed_ln_kernel<<<MROWS/4, 256, 0, stream>>>(vm_states, num_step, pm_states,
                                                 pm_W, pm_b, vm_W, vm_b,
                                                 ln1g, ln1b, x, hbuf);
    for (int i=0;i<3;i++){
        mgemm_kernel<0><<<dim3(768/128, MROWS/128),256,0,stream>>>(
            hbuf, wq + (size_t)i*768*256, bqkv + i*768, qkv, 768, 256);
        attn_kernel<<<MROWS/4, 256, 0, stream>>>(qkv, rel, counts, offs, members, aout);
        mgemm2ln_kernel<1><<<MROWS/32,256,0,stream>>>(
            aout, wo + (size_t)i*256*256, bo + i*DD, ln2g + i*DD, ln2b + i*DD, x, hbuf, 256);
        mgemm_kernel<2><<<dim3(1024/128, MROWS/128),256,0,stream>>>(
            hbuf, w1 + (size_t)i*1024*256, b1 + i*FF, ff1, 1024, 256);
        if (i < 2)
            mgemm2ln_kernel<1><<<MROWS/32,256,0,stream>>>(
                ff1, w2 + (size_t)i*256*1024, b2 + i*DD, ln1g + (i+1)*DD, ln1b + (i+1)*DD, x, hbuf, 1024);
        else
            mgemm2ln_kernel<0><<<MROWS/32,256,0,stream>>>(
                ff1, w2 + (size_t)i*256*1024, b2 + i*DD, nullptr, nullptr, x, nullptr, 1024);
    }
    out_kernel<<<(NB*769+3)/4, 256, 0, stream>>>(x, out_W, out_b, crit_W, crit_b, (float*)d_out);
}

// Round 7
// 332.861 us; speedup vs baseline: 1.0862x; 1.0862x over previous
//
#include <hip/hip_runtime.h>
#include <hip/hip_bf16.h>
#include <math.h>

#define NUM_PM 254
#define NUM_VM 768
#define SEQQ   1024      // NUM_PM + NUM_VM + 2
#define NH     8
#define DD     256
#define DH     32
#define FF     1024
#define NB     8
#define MROWS  (NB*SEQQ) // 8192

typedef unsigned short u16;
typedef __attribute__((ext_vector_type(8))) short bf16x8;
typedef __attribute__((ext_vector_type(4))) float f32x4;

__device__ __forceinline__ float bf2f(u16 u){
    union { float f; unsigned int i; } c; c.i = ((unsigned int)u) << 16; return c.f;
}
__device__ __forceinline__ u16 f2bf(float f){
    union { float f; unsigned int u; } c; c.f = f;
    unsigned int r = c.u + 0x7FFFu + ((c.u >> 16) & 1u);   // RNE
    return (u16)(r >> 16);
}
__device__ __forceinline__ float gelu_tanh(float x){
    float x3 = x*x*x;
    float t = tanhf(0.7978845608028654f*(x + 0.044715f*x3));
    return 0.5f*x*(1.0f+t);
}

#define GLOAD16(gp, lp) __builtin_amdgcn_global_load_lds( \
    (const __attribute__((address_space(1))) void*)(gp), \
    (__attribute__((address_space(3))) void*)(lp), 16, 0, 0)

// ---------------------------------------------------------------- prologue: tcast (0..2303) | group build (2304..2311) | embed+LN1 (2312..4359)
__global__ void prologue_kernel(const float* __restrict__ Wqkv, const float* __restrict__ Wo,
                                const float* __restrict__ W1,   const float* __restrict__ W2,
                                u16* __restrict__ wq, u16* __restrict__ wo,
                                u16* __restrict__ w1, u16* __restrict__ w2,
                                const int* __restrict__ rel, const unsigned char* __restrict__ mask,
                                int* __restrict__ counts, int* __restrict__ offs,
                                int* __restrict__ members,
                                const float* __restrict__ vm_states,
                                const float* __restrict__ num_step,
                                const float* __restrict__ pm_states,
                                const float* __restrict__ pm_W, const float* __restrict__ pm_b,
                                const float* __restrict__ vm_W, const float* __restrict__ vm_b,
                                const float* __restrict__ g, const float* __restrict__ beta,
                                float* __restrict__ x, u16* __restrict__ h)
{
    __shared__ float t[32][33];
    __shared__ int cntS[256], offS[256], wsum4[4];
    int bid = blockIdx.x;
    int tid = threadIdx.x;
    if (bid < 2304){
        // ---- transpose-cast one 32x32 tile
        int id = bid;
        const float* in; u16* out; int K, N, layer, tile;
        if (id < 576)       { in=Wqkv; out=wq; K=256;  N=768;  layer=id/192; tile=id%192; }
        else if (id < 768)  { id-=576;  in=Wo; out=wo; K=256;  N=256;  layer=id/64;  tile=id%64;  }
        else if (id < 1536) { id-=768;  in=W1; out=w1; K=256;  N=1024; layer=id/256; tile=id%256; }
        else                { id-=1536; in=W2; out=w2; K=1024; N=256;  layer=id/256; tile=id%256; }
        int ntx = N/32;
        int n0 = (tile % ntx)*32, k0 = (tile / ntx)*32;
        size_t lofs = (size_t)layer * K * N;
        int tx = tid & 31, ty = tid >> 5;
        #pragma unroll
        for (int i=0;i<4;i++)
            t[ty + i*8][tx] = in[lofs + (size_t)(k0 + ty + i*8)*N + n0 + tx];
        __syncthreads();
        #pragma unroll
        for (int i=0;i<4;i++)
            out[lofs + (size_t)(n0 + ty + i*8)*K + k0 + tx] = f2bf(t[tx][ty + i*8]);
    } else if (bid < 2312){
        // ---- group build for batch b (counting sort by code)
        int b = bid - 2304;
        cntS[tid] = 0;
        __syncthreads();
        int myc[4], myp[4];
        #pragma unroll
        for (int si=0; si<4; si++){
            int s = si*256 + tid;
            bool valid = (s != 0) && (s != SEQQ-1);
            if (valid && s >= 1+NUM_PM && mask[b*NUM_VM + (s-1-NUM_PM)]) valid = false;
            myc[si] = -1;
            if (valid){
                myc[si] = rel[b*(SEQQ-2) + s-1];
                myp[si] = atomicAdd(&cntS[myc[si]], 1);
            }
        }
        __syncthreads();
        int v = cntS[tid];
        int incl = v;
        #pragma unroll
        for (int d=1; d<64; d<<=1){
            int n = __shfl_up(incl, d);
            if ((tid & 63) >= d) incl += n;
        }
        offS[tid] = incl - v;
        if ((tid & 63) == 63) wsum4[tid>>6] = incl;
        __syncthreads();
        {
            int w = tid >> 6, base = 0;
            #pragma unroll
            for (int i=0;i<4;i++) if (i < w) base += wsum4[i];
            offS[tid] += base;
        }
        __syncthreads();
        #pragma unroll
        for (int si=0; si<4; si++)
            if (myc[si] >= 0)
                members[b*SEQQ + offS[myc[si]] + myp[si]] = si*256 + tid;
        counts[b*256 + tid] = cntS[tid];
        offs[b*256 + tid]   = offS[tid];
    } else {
        // ---- embed + LN1(layer0): wave per row
        int row = (bid - 2312)*4 + (tid>>6);
        int lane = tid & 63;
        int b = row >> 10, s = row & 1023;
        int col = lane*4;
        float4 out;
        if (s == 0){
            float v = num_step[b]; out = (float4){v,v,v,v};
        } else if (s == SEQQ-1){
            out = (float4){-1.f,-1.f,-1.f,-1.f};
        } else {
            const float* in; const float* W; const float* bias;
            if (s <= NUM_PM){ in = pm_states + (size_t)(b*NUM_PM + s-1)*16; W = pm_W; bias = pm_b; }
            else            { in = vm_states + (size_t)(b*NUM_VM + (s-1-NUM_PM))*16; W = vm_W; bias = vm_b; }
            float4 i0 = *(const float4*)in,      i1 = *(const float4*)(in+4);
            float4 i2 = *(const float4*)(in+8),  i3 = *(const float4*)(in+12);
            float in16[16] = {i0.x,i0.y,i0.z,i0.w, i1.x,i1.y,i1.z,i1.w,
                              i2.x,i2.y,i2.z,i2.w, i3.x,i3.y,i3.z,i3.w};
            out = *(const float4*)&bias[col];
            #pragma unroll
            for (int k=0;k<16;k++){
                float4 w4 = *(const float4*)&W[k*DD + col];
                out.x = fmaf(in16[k], w4.x, out.x);
                out.y = fmaf(in16[k], w4.y, out.y);
                out.z = fmaf(in16[k], w4.z, out.z);
                out.w = fmaf(in16[k], w4.w, out.w);
            }
        }
        *(float4*)&x[(size_t)row*DD + col] = out;
        float s1 = out.x+out.y+out.z+out.w;
        float s2 = fmaf(out.x,out.x, fmaf(out.y,out.y, fmaf(out.z,out.z, out.w*out.w)));
        #pragma unroll
        for (int off=1; off<64; off<<=1){ s1 += __shfl_xor(s1,off); s2 += __shfl_xor(s2,off); }
        float m    = s1*(1.0f/DD);
        float var  = s2*(1.0f/DD) - m*m;
        float rstd = rsqrtf(var + 1e-5f);
        float4 g4 = *(const float4*)&g[col];
        float4 b4 = *(const float4*)&beta[col];
        short4 o;
        o.x = (short)f2bf((out.x-m)*rstd*g4.x + b4.x);
        o.y = (short)f2bf((out.y-m)*rstd*g4.y + b4.y);
        o.z = (short)f2bf((out.z-m)*rstd*g4.z + b4.z);
        o.w = (short)f2bf((out.w-m)*rstd*g4.w + b4.w);
        *(short4*)&h[(size_t)row*DD + col] = o;
    }
}

// ---------------------------------------------------------------- layernorm: wave per row, f32 in -> bf16 out
__global__ void ln_kernel(const float* __restrict__ x, const float* __restrict__ g,
                          const float* __restrict__ bta, u16* __restrict__ out)
{
    int row = blockIdx.x*4 + (threadIdx.x>>6);
    int lane = threadIdx.x & 63;
    const float4 v = *(const float4*)&x[(size_t)row*DD + lane*4];
    float s1 = v.x+v.y+v.z+v.w;
    float s2 = fmaf(v.x,v.x, fmaf(v.y,v.y, fmaf(v.z,v.z, v.w*v.w)));
    #pragma unroll
    for (int off=1; off<64; off<<=1){ s1 += __shfl_xor(s1,off); s2 += __shfl_xor(s2,off); }
    float m    = s1*(1.0f/DD);
    float var  = s2*(1.0f/DD) - m*m;
    float rstd = rsqrtf(var + 1e-5f);
    float4 g4 = *(const float4*)&g[lane*4];
    float4 b4 = *(const float4*)&bta[lane*4];
    short4 o;
    o.x = (short)f2bf((v.x-m)*rstd*g4.x + b4.x);
    o.y = (short)f2bf((v.y-m)*rstd*g4.y + b4.y);
    o.z = (short)f2bf((v.z-m)*rstd*g4.z + b4.z);
    o.w = (short)f2bf((v.w-m)*rstd*g4.w + b4.w);
    *(short4*)&out[(size_t)row*DD + lane*4] = o;
}

// ---------------------------------------------------------------- MFMA GEMM 64x128, dbuf: C bf16 = A@Bt^T + bias   (QKV)
__launch_bounds__(256)
__global__ void qgemm_kernel(const u16* __restrict__ A, const u16* __restrict__ Bt,
                             const float* __restrict__ bias, u16* __restrict__ C,
                             int N, int K)
{
    __shared__ u16 As[2][64][32];
    __shared__ u16 Bs[2][128][32];
    int tid = threadIdx.x;
    int wid = tid >> 6, lane = tid & 63;
    int wr = wid >> 1, wc = wid & 1;            // wave tile 32x64
    int row0 = blockIdx.y*64, col0 = blockIdx.x*128;
    int l15 = lane & 15, lh = lane >> 4;

    const u16* Ag = A  + (size_t)(row0 + wid*16 + (lane>>2))*K + (lane&3)*8;
    const u16* Bg = Bt + (size_t)(col0 + wid*32 + (lane>>2))*K + (lane&3)*8;

#define STAGE_Q(buf, k0) do{ \
    GLOAD16(Ag + (k0),          &As[buf][wid*16][0]);    \
    GLOAD16(Bg + (k0),          &Bs[buf][wid*32][0]);    \
    GLOAD16(Bg + (k0) + 16*K,   &Bs[buf][wid*32+16][0]); }while(0)

    f32x4 acc[2][4] = {};
    int nk = K >> 5;
    STAGE_Q(0, 0);
    __syncthreads();
    for (int kt = 0; kt < nk; kt++){
        int cur = kt & 1;
        if (kt+1 < nk) STAGE_Q(cur^1, (kt+1)*32);
        bf16x8 af[2], bfv[4];
        #pragma unroll
        for (int i=0;i<2;i++)
            af[i] = *(const bf16x8*)&As[cur][wr*32 + i*16 + l15][lh*8];
        #pragma unroll
        for (int j=0;j<4;j++)
            bfv[j] = *(const bf16x8*)&Bs[cur][wc*64 + j*16 + l15][lh*8];
        #pragma unroll
        for (int i=0;i<2;i++)
            #pragma unroll
            for (int j=0;j<4;j++)
                acc[i][j] = __builtin_amdgcn_mfma_f32_16x16x32_bf16(af[i], bfv[j], acc[i][j], 0,0,0);
        __syncthreads();
    }
#undef STAGE_Q

    #pragma unroll
    for (int i=0;i<2;i++){
        #pragma unroll
        for (int j=0;j<4;j++){
            int col = col0 + wc*64 + j*16 + l15;
            float bb = bias[col];
            #pragma unroll
            for (int r=0;r<4;r++){
                int row = row0 + wr*32 + i*16 + lh*4 + r;
                C[(size_t)row*N + col] = f2bf(acc[i][j][r] + bb);
            }
        }
    }
}

// ---------------------------------------------------------------- MFMA GEMM 128x128, dbuf: C bf16 = gelu(A@Bt^T + bias)   (FF1)
__launch_bounds__(256)
__global__ void mgemm_kernel(const u16* __restrict__ A, const u16* __restrict__ Bt,
                             const float* __restrict__ bias, u16* __restrict__ C,
                             int N, int K)
{
    __shared__ u16 As[2][128][32];
    __shared__ u16 Bs[2][128][32];
    int tid = threadIdx.x;
    int wid = tid >> 6, lane = tid & 63;
    int wr = wid >> 1, wc = wid & 1;
    int row0 = blockIdx.y*128, col0 = blockIdx.x*128;
    int l15 = lane & 15, lh = lane >> 4;

    const u16* Ag = A  + (size_t)(row0 + wid*32 + (lane>>2))*K + (lane&3)*8;
    const u16* Bg = Bt + (size_t)(col0 + wid*32 + (lane>>2))*K + (lane&3)*8;

#define STAGE_M(buf, k0) do{ \
    GLOAD16(Ag + (k0),          &As[buf][wid*32][0]);    \
    GLOAD16(Ag + (k0) + 16*K,   &As[buf][wid*32+16][0]); \
    GLOAD16(Bg + (k0),          &Bs[buf][wid*32][0]);    \
    GLOAD16(Bg + (k0) + 16*K,   &Bs[buf][wid*32+16][0]); }while(0)

    f32x4 acc[4][4] = {};
    int nk = K >> 5;
    STAGE_M(0, 0);
    __syncthreads();
    for (int kt = 0; kt < nk; kt++){
        int cur = kt & 1;
        if (kt+1 < nk) STAGE_M(cur^1, (kt+1)*32);
        bf16x8 af[4], bfv[4];
        #pragma unroll
        for (int f=0; f<4; f++){
            af[f]  = *(const bf16x8*)&As[cur][wr*64 + f*16 + l15][lh*8];
            bfv[f] = *(const bf16x8*)&Bs[cur][wc*64 + f*16 + l15][lh*8];
        }
        #pragma unroll
        for (int i=0;i<4;i++)
            #pragma unroll
            for (int j=0;j<4;j++)
                acc[i][j] = __builtin_amdgcn_mfma_f32_16x16x32_bf16(af[i], bfv[j], acc[i][j], 0,0,0);
        __syncthreads();
    }
#undef STAGE_M

    #pragma unroll
    for (int i=0;i<4;i++){
        #pragma unroll
        for (int j=0;j<4;j++){
            int col = col0 + wc*64 + j*16 + l15;
            float bb = bias[col];
            #pragma unroll
            for (int r=0;r<4;r++){
                int row = row0 + wr*64 + i*16 + lh*4 + r;
                C[(size_t)row*N + col] = f2bf(gelu_tanh(acc[i][j][r] + bb));
            }
        }
    }
}

// ---------------------------------------------------------------- MFMA GEMM 64x64, dbuf: x[M,256] += A@Bt^T + bias  (+head)
// HEAD=1: also emit per-row dots with out_W/crit_W into out via atomicAdd (out pre-zeroed)
template<int HEAD>
__launch_bounds__(256)
__global__ void mgemm64_kernel(const u16* __restrict__ A, const u16* __restrict__ Bt,
                               const float* __restrict__ bias, float* __restrict__ x,
                               const float* __restrict__ out_W, const float* __restrict__ out_b,
                               const float* __restrict__ crit_W, const float* __restrict__ crit_b,
                               float* __restrict__ out, int K)
{
    __shared__ u16 As[2][64][32];
    __shared__ u16 Bs[2][64][32];
    int tid = threadIdx.x;
    int wid = tid >> 6, lane = tid & 63;
    int wr = wid >> 1, wc = wid & 1;            // wave tile 32x32
    int row0 = blockIdx.y*64, col0 = blockIdx.x*64;
    int l15 = lane & 15, lh = lane >> 4;

    const u16* Ag = A  + (size_t)(row0 + wid*16 + (lane>>2))*K + (lane&3)*8;
    const u16* Bg = Bt + (size_t)(col0 + wid*16 + (lane>>2))*K + (lane&3)*8;

#define STAGE_S(buf, k0) do{ \
    GLOAD16(Ag + (k0), &As[buf][wid*16][0]); \
    GLOAD16(Bg + (k0), &Bs[buf][wid*16][0]); }while(0)

    f32x4 acc[2][2] = {};
    int nk = K >> 5;
    STAGE_S(0, 0);
    __syncthreads();
    for (int kt = 0; kt < nk; kt++){
        int cur = kt & 1;
        if (kt+1 < nk) STAGE_S(cur^1, (kt+1)*32);
        bf16x8 af[2], bfv[2];
        #pragma unroll
        for (int i=0;i<2;i++)
            af[i] = *(const bf16x8*)&As[cur][wr*32 + i*16 + l15][lh*8];
        #pragma unroll
        for (int j=0;j<2;j++)
            bfv[j] = *(const bf16x8*)&Bs[cur][wc*32 + j*16 + l15][lh*8];
        #pragma unroll
        for (int i=0;i<2;i++)
            #pragma unroll
            for (int j=0;j<2;j++)
                acc[i][j] = __builtin_amdgcn_mfma_f32_16x16x32_bf16(af[i], bfv[j], acc[i][j], 0,0,0);
        __syncthreads();
    }
#undef STAGE_S

    #pragma unroll
    for (int i=0;i<2;i++){
        #pragma unroll
        for (int r=0;r<4;r++){
            int row = row0 + wr*32 + i*16 + lh*4 + r;
            float hp = 0.f;     // head partial over this lane's 2 cols
            bool do_head = false;
            int s = row & 1023;
            #pragma unroll
            for (int j=0;j<2;j++){
                int col = col0 + wc*32 + j*16 + l15;
                size_t idx = (size_t)row*DD + col;
                float v = acc[i][j][r] + bias[col] + x[idx];
                x[idx] = v;
                if (HEAD){
                    float w = (s == 1023) ? crit_W[col] : out_W[col];
                    hp = fmaf(v, w, hp);
                }
            }
            if (HEAD && s >= 1 + NUM_PM){
                do_head = true;
                hp += __shfl_xor(hp, 1);
                hp += __shfl_xor(hp, 2);
                hp += __shfl_xor(hp, 4);
                hp += __shfl_xor(hp, 8);
                if (l15 == 0){
                    int b = row >> 10;
                    int jj = (s == 1023) ? 768 : (s - (1 + NUM_PM));
                    float add = hp;
                    if (blockIdx.x == 0 && wc == 0)
                        add += (s == 1023) ? crit_b[0] : out_b[0];
                    atomicAdd(&out[b*769 + jj], add);
                }
            }
            (void)do_head;
        }
    }
}

// ---------------------------------------------------------------- attention (gathered group-sparse, bf16, chunked prefetch)
__launch_bounds__(256)
__global__ void attn_kernel(const u16* __restrict__ qkv, const int* __restrict__ rel,
                            const int* __restrict__ counts, const int* __restrict__ offs,
                            const int* __restrict__ members, u16* __restrict__ o)
{
    int gq = blockIdx.x*4 + (threadIdx.x >> 6);
    int lane = threadIdx.x & 63;
    int b = gq >> 10, s = gq & 1023;
    const float scale = 0.17677669529663687f;       // 1/sqrt(32)

    const u16* base = qkv + (size_t)(b*SEQQ + s)*768 + lane*4;
    short4 q4i = *(const short4*)base;
    float qx = bf2f((u16)q4i.x)*scale, qy = bf2f((u16)q4i.y)*scale,
          qz = bf2f((u16)q4i.z)*scale, qw = bf2f((u16)q4i.w)*scale;

    int cnt; const int* mlist = nullptr;
    if (s == 0 || s == SEQQ-1) { cnt = 1; }
    else {
        int c = rel[b*(SEQQ-2) + s-1];
        cnt   = counts[b*256 + c];
        mlist = members + b*SEQQ + offs[b*256 + c];
    }

    float m_run = -1e30f, l_run = 0.f;
    float ax=0.f, ay=0.f, az=0.f, aw=0.f;
    for (int j0 = 0; j0 < cnt; j0 += 4){
        short4 k4[4], v4[4];
        #pragma unroll
        for (int k=0;k<4;k++){
            int jj = j0 + k; jj = (jj < cnt) ? jj : (cnt-1);
            int mi = mlist ? mlist[jj] : s;
            const u16* kb = qkv + (size_t)(b*SEQQ + mi)*768 + 256 + lane*4;
            k4[k] = *(const short4*)kb;
            v4[k] = *(const short4*)(kb + 256);
        }
        #pragma unroll
        for (int k=0;k<4;k++){
            if (j0 + k < cnt){
                float sc = qx*bf2f((u16)k4[k].x) + qy*bf2f((u16)k4[k].y)
                         + qz*bf2f((u16)k4[k].z) + qw*bf2f((u16)k4[k].w);
                sc += __shfl_xor(sc, 1);
                sc += __shfl_xor(sc, 2);
                sc += __shfl_xor(sc, 4);
                float mn = fmaxf(m_run, sc);
                float corr = __expf(m_run - mn);
                float p = __expf(sc - mn);
                l_run = l_run*corr + p;
                ax = ax*corr + p*bf2f((u16)v4[k].x);
                ay = ay*corr + p*bf2f((u16)v4[k].y);
                az = az*corr + p*bf2f((u16)v4[k].z);
                aw = aw*corr + p*bf2f((u16)v4[k].w);
                m_run = mn;
            }
        }
    }
    float inv = (l_run > 0.f) ? 1.0f/l_run : 0.f;
    u16* orow = o + (size_t)(b*SEQQ + s)*DD + lane*4;
    short4 outv;
    outv.x = (short)f2bf(ax*inv); outv.y = (short)f2bf(ay*inv);
    outv.z = (short)f2bf(az*inv); outv.w = (short)f2bf(aw*inv);
    *(short4*)orow = outv;
}

// ---------------------------------------------------------------- launch
extern "C" void kernel_launch(void* const* d_in, const int* in_sizes, int n_in,
                              void* d_out, int out_size, void* d_ws, size_t ws_size,
                              hipStream_t stream)
{
    const float* vm_states = (const float*)d_in[0];
    const float* num_step  = (const float*)d_in[1];
    const float* pm_states = (const float*)d_in[2];
    const int*   rel       = (const int*)d_in[3];
    const unsigned char* mask = (const unsigned char*)d_in[4];
    const float* pm_W = (const float*)d_in[5];
    const float* pm_b = (const float*)d_in[6];
    const float* vm_W = (const float*)d_in[7];
    const float* vm_b = (const float*)d_in[8];
    const float* Wqkv = (const float*)d_in[9];
    const float* bqkv = (const float*)d_in[10];
    const float* Wo   = (const float*)d_in[11];
    const float* bo   = (const float*)d_in[12];
    const float* ln1g = (const float*)d_in[13];
    const float* ln1b = (const float*)d_in[14];
    const float* ln2g = (const float*)d_in[15];
    const float* ln2b = (const float*)d_in[16];
    const float* W1   = (const float*)d_in[17];
    const float* b1   = (const float*)d_in[18];
    const float* W2   = (const float*)d_in[19];
    const float* b2   = (const float*)d_in[20];
    const float* out_W = (const float*)d_in[21];
    const float* out_b = (const float*)d_in[22];
    const float* crit_W = (const float*)d_in[23];
    const float* crit_b = (const float*)d_in[24];

    char* ws = (char*)d_ws;
    const size_t MB = 1024*1024;
    float* x    = (float*)(ws);                      // [8192][256] f32   :  0..8 MB
    u16*   hbuf = (u16*)(ws + 8*MB);                 // [8192][256] bf16  :  8..12
    u16*   aout = (u16*)(ws + 12*MB);                // [8192][256] bf16  : 12..16
    u16*   qkv  = (u16*)(ws + 16*MB);                // [8192][768] bf16  : 16..28
    u16*   ff1  = (u16*)(ws + 28*MB);                // [8192][1024] bf16 : 28..44
    u16*   wq   = (u16*)(ws + 44*MB);                // [3][768][256]
    u16*   wo   = wq + (size_t)3*768*256;            // [3][256][256]
    u16*   w1   = wo + (size_t)3*256*256;            // [3][1024][256]
    u16*   w2   = w1 + (size_t)3*1024*256;           // [3][256][1024]
    int*   counts  = (int*)(ws + 50*MB);             // [8][256]
    int*   offs    = counts + NB*256;
    int*   members = offs   + NB*256;                // [8][1024]

    hipMemsetAsync(d_out, 0, (size_t)out_size*sizeof(float), stream);
    prologue_kernel<<<4360, 256, 0, stream>>>(Wqkv, Wo, W1, W2, wq, wo, w1, w2,
                                              rel, mask, counts, offs, members,
                                              vm_states, num_step, pm_states,
                                              pm_W, pm_b, vm_W, vm_b,
                                              ln1g, ln1b, x, hbuf);
    for (int i=0;i<3;i++){
        qgemm_kernel<<<dim3(768/128, MROWS/64),256,0,stream>>>(
            hbuf, wq + (size_t)i*768*256, bqkv + i*768, qkv, 768, 256);
        attn_kernel<<<MROWS/4, 256, 0, stream>>>(qkv, rel, counts, offs, members, aout);
        mgemm64_kernel<0><<<dim3(256/64, MROWS/64),256,0,stream>>>(
            aout, wo + (size_t)i*256*256, bo + i*DD, x,
            nullptr, nullptr, nullptr, nullptr, nullptr, 256);
        ln_kernel<<<MROWS/4,256,0,stream>>>(x, ln2g + i*DD, ln2b + i*DD, hbuf);
        mgemm_kernel<<<dim3(1024/128, MROWS/128),256,0,stream>>>(
            hbuf, w1 + (size_t)i*1024*256, b1 + i*FF, ff1, 1024, 256);
        if (i < 2){
            mgemm64_kernel<0><<<dim3(256/64, MROWS/64),256,0,stream>>>(
                ff1, w2 + (size_t)i*256*1024, b2 + i*DD, x,
                nullptr, nullptr, nullptr, nullptr, nullptr, 1024);
            ln_kernel<<<MROWS/4,256,0,stream>>>(x, ln1g + (i+1)*DD, ln1b + (i+1)*DD, hbuf);
        } else {
            mgemm64_kernel<1><<<dim3(256/64, MROWS/64),256,0,stream>>>(
                ff1, w2 + (size_t)i*256*1024, b2 + i*DD, x,
                out_W, out_b, crit_W, crit_b, (float*)d_out, 1024);
        }
    }
}